// Round 17
// baseline (251.791 us; speedup 1.0000x reference)
//
#include <hip/hip_runtime.h>
#include <hip/hip_bf16.h>

// ---------------------------------------------------------------------------
// EnhancedTernaryLinear: out = (x @ W^T) * scale + bias
// M=8192, N=4096, K=4096. Fused x->bf16 / W->bf16 conversion (one launch),
// then the R5 champion 256x256 MFMA GEMM (4-phase read-ahead pipeline,
// counted lgkmcnt + sched_barrier, one barrier per phase, XOR-swizzled LDS,
// XCD-swizzled grid), + LDS-transposed vectorized epilogue (dwordx4 stores).
// FINAL configuration (R16 locked in): 251.5 us total, gemm ~225 us at
// ~50% of dense bf16 peak, writes at compulsory-traffic efficiency.
// ---------------------------------------------------------------------------

#define M_DIM 8192
#define N_DIM 4096
#define K_DIM 4096
#define BK 64
#define NT (K_DIM / BK)   // 64 K-tiles

typedef __attribute__((ext_vector_type(8))) short bf16x8;
typedef __attribute__((ext_vector_type(4))) float f32x4;

__device__ __forceinline__ unsigned short f2bf(float f) {
  unsigned int u = __float_as_uint(f);
  unsigned int r = (u + 0x7FFFu + ((u >> 16) & 1u)) >> 16;
  return (unsigned short)r;
}

__device__ __forceinline__ unsigned short i2bf(int v) {
  return v == 0 ? (unsigned short)0
                : (v > 0 ? (unsigned short)0x3F80 : (unsigned short)0xBF80);
}

__device__ __forceinline__ void async16(const void* g, void* l) {
  __builtin_amdgcn_global_load_lds(
      (const __attribute__((address_space(1))) void*)g,
      (__attribute__((address_space(3))) void*)l, 16, 0, 0);
}

// ---------------- fused conversion kernel (one launch) ----------------

__global__ void cvt_fused_kernel(const float* __restrict__ x,
                                 const int* __restrict__ w,
                                 unsigned short* __restrict__ xb,
                                 unsigned short* __restrict__ wb,
                                 long nx, long nw) {
  long i0 = ((long)blockIdx.x * blockDim.x + threadIdx.x) * 8;
  long stride = (long)gridDim.x * blockDim.x * 8;
  for (long i = i0; i < nx; i += stride) {
    float4 v0 = *(const float4*)(x + i);
    float4 v1 = *(const float4*)(x + i + 4);
    bf16x8 o;
    o[0] = (short)f2bf(v0.x); o[1] = (short)f2bf(v0.y);
    o[2] = (short)f2bf(v0.z); o[3] = (short)f2bf(v0.w);
    o[4] = (short)f2bf(v1.x); o[5] = (short)f2bf(v1.y);
    o[6] = (short)f2bf(v1.z); o[7] = (short)f2bf(v1.w);
    *(bf16x8*)(xb + i) = o;
  }
  for (long i = i0; i < nw; i += stride) {
    int4 a = *(const int4*)(w + i);
    int4 b = *(const int4*)(w + i + 4);
    bf16x8 o;
    o[0] = (short)i2bf(a.x); o[1] = (short)i2bf(a.y);
    o[2] = (short)i2bf(a.z); o[3] = (short)i2bf(a.w);
    o[4] = (short)i2bf(b.x); o[5] = (short)i2bf(b.y);
    o[6] = (short)i2bf(b.z); o[7] = (short)i2bf(b.w);
    *(bf16x8*)(wb + i) = o;
  }
}

// ---------------- 256x256 GEMM, 4 phases/K-tile, read-ahead 1 phase -------
// (champion loop — unchanged from R5/R13; see prior round comments)

#define AOFF(b, mh) ((b)*32768 + (mh)*8192)
#define BOFF(b, nh) ((b)*32768 + 16384 + (nh)*8192)

__device__ __forceinline__ void stage_A_half(const unsigned short* __restrict__ A,
                                             int grow0, int ktE, int mh,
                                             unsigned short* lds_region, int t) {
  const int colb = (t & 7) * 16;
  const int swz = ((t >> 3) & 7) << 4;
  const int scol = (colb ^ swz) >> 1;  // element offset in row
#pragma unroll
  for (int rr = 0; rr < 2; ++rr) {
    int rho = rr * 64 + (t >> 3);
    int r = ((rho >> 6) << 7) + mh * 64 + (rho & 63);
    async16(A + (size_t)(grow0 + r) * K_DIM + ktE + scol,
            lds_region + rr * 4096 + t * 8);
  }
}

__device__ __forceinline__ void stage_B_half(const unsigned short* __restrict__ B,
                                             int gcol0, int ktE, int nh,
                                             unsigned short* lds_region, int t) {
  const int colb = (t & 7) * 16;
  const int swz = ((t >> 3) & 7) << 4;
  const int scol = (colb ^ swz) >> 1;
#pragma unroll
  for (int rr = 0; rr < 2; ++rr) {
    int rho = rr * 64 + (t >> 3);
    int c = ((rho >> 5) << 6) + nh * 32 + (rho & 31);
    async16(B + (size_t)(gcol0 + c) * K_DIM + ktE + scol,
            lds_region + rr * 4096 + t * 8);
  }
}

#define DSR(dst, base, OFF)                                     \
  asm volatile("ds_read_b128 %0, %1 offset:" OFF                \
               : "=v"(dst) : "v"(base))

__device__ __forceinline__ void rd_a(unsigned b0, bf16x8 aF[4][2]) {
  unsigned b1 = b0 ^ 64;  // kk=1 (byte col ^64, swizzle-compatible)
  DSR(aF[0][0], b0, "0");    DSR(aF[0][1], b1, "0");
  DSR(aF[1][0], b0, "2048"); DSR(aF[1][1], b1, "2048");
  DSR(aF[2][0], b0, "4096"); DSR(aF[2][1], b1, "4096");
  DSR(aF[3][0], b0, "6144"); DSR(aF[3][1], b1, "6144");
}
__device__ __forceinline__ void rd_b(unsigned b0, bf16x8 bF[2][2]) {
  unsigned b1 = b0 ^ 64;
  DSR(bF[0][0], b0, "0");    DSR(bF[0][1], b1, "0");
  DSR(bF[1][0], b0, "2048"); DSR(bF[1][1], b1, "2048");
}

#define LGKM(N)                                                  \
  asm volatile("s_waitcnt lgkmcnt(" #N ")" ::: "memory");        \
  __builtin_amdgcn_sched_barrier(0)
#define VMW(N) asm volatile("s_waitcnt vmcnt(" #N ")" ::: "memory")

#define MFMA16(AF, BF, MH, NH)                                                 \
  do {                                                                         \
    __builtin_amdgcn_s_setprio(1);                                             \
    _Pragma("unroll") for (int kk = 0; kk < 2; ++kk)                           \
    _Pragma("unroll") for (int mi = 0; mi < 4; ++mi)                           \
    _Pragma("unroll") for (int ni = 0; ni < 2; ++ni)                           \
      acc[(MH)*4 + mi][(NH)*2 + ni] = __builtin_amdgcn_mfma_f32_16x16x32_bf16( \
          AF[mi][kk], BF[ni][kk], acc[(MH)*4 + mi][(NH)*2 + ni], 0, 0, 0);     \
    __builtin_amdgcn_s_setprio(0);                                             \
    __builtin_amdgcn_sched_barrier(0);                                         \
  } while (0)

__global__ void __launch_bounds__(512, 2)
gemm_bt_kernel(const unsigned short* __restrict__ A,  // bf16 [M][K]
               const unsigned short* __restrict__ B,  // bf16 [N][K]
               const float* __restrict__ scale, const float* __restrict__ bias,
               float* __restrict__ C) {
  __shared__ unsigned short lds[65536];  // 128 KiB

  const int t = threadIdx.x;
  const int bid = blockIdx.x;
  const int swz = (bid & 7) * 64 + (bid >> 3);  // 512 wgs, 64/XCD (bijective)
  const int bm = swz >> 4;  // 32 M-tiles
  const int bn = swz & 15;  // 16 N-tiles
  const int brow = bm * 256, bcol = bn * 256;

  const int wid = t >> 6, lane = t & 63;
  const int wr = wid >> 2, wc = wid & 3;
  const int fr = lane & 15, fq = lane >> 4;

  // ds_read base addresses (LDS byte offsets; low 32 bits of generic ptr)
  const unsigned ldsb = (unsigned)(unsigned long long)&lds[0];
  const unsigned swzcol = ((unsigned)(fq * 16)) ^ ((unsigned)((fr & 7) << 4));
  const unsigned rcA = ldsb + (unsigned)((wr * 64 + fr) * 128) + swzcol;
  const unsigned rcB = ldsb + (unsigned)((wc * 32 + fr) * 128) + swzcol;

  f32x4 acc[8][4] = {};
  bf16x8 aFx[4][2], aFy[4][2], bF0[2][2], bF1[2][2], bF0n[2][2];

  // ---- prologue: tile0 (4 halves) + tile1 {A-mh0, B-nh1, A-mh1} ----
  stage_A_half(A, brow, 0, 0, lds + AOFF(0, 0), t);
  stage_B_half(B, bcol, 0, 1, lds + BOFF(0, 1), t);
  stage_A_half(A, brow, 0, 1, lds + AOFF(0, 1), t);
  stage_B_half(B, bcol, 0, 0, lds + BOFF(0, 0), t);
  stage_A_half(A, brow, BK, 0, lds + AOFF(1, 0), t);
  stage_B_half(B, bcol, BK, 1, lds + BOFF(1, 1), t);
  stage_A_half(A, brow, BK, 1, lds + AOFF(1, 1), t);
  VMW(6);  // tile0's 8 stage-loads landed
  __builtin_amdgcn_s_barrier();
  rd_a(rcA + ((unsigned)AOFF(0, 0) << 1), aFx);
  rd_b(rcB + ((unsigned)BOFF(0, 0) << 1), bF0);

  for (int T = 0; T < NT; ++T) {
    const int b = T & 1;

    // -- q0: MFMA(mh0,nh0); issue bF1(T) reads; stage B-nh0(T+1)
    rd_b(rcB + ((unsigned)BOFF(b, 1) << 1), bF1);
    if (T + 1 < NT) stage_B_half(B, bcol, (T + 1) * BK, 0, lds + BOFF(b ^ 1, 0), t);
    LGKM(4);
    MFMA16(aFx, bF0, 0, 0);
    __builtin_amdgcn_s_barrier();

    // -- q1: MFMA(mh0,nh1); issue aFy(T) reads; stage A-mh0(T+2)
    rd_a(rcA + ((unsigned)AOFF(b, 1) << 1), aFy);
    if (T + 2 < NT) stage_A_half(A, brow, (T + 2) * BK, 0, lds + AOFF(b, 0), t);
    LGKM(8);
    MFMA16(aFx, bF1, 0, 1);
    __builtin_amdgcn_s_barrier();

    // -- q2: MFMA(mh1,nh1); no reads; stage B-nh1(T+2); vmcnt once/tile
    if (T + 2 < NT) stage_B_half(B, bcol, (T + 2) * BK, 1, lds + BOFF(b, 1), t);
    LGKM(0);
    MFMA16(aFy, bF1, 1, 1);
    if (T < NT - 2)
      VMW(4);
    else if (T == NT - 2)
      VMW(0);
    __builtin_amdgcn_s_barrier();

    // -- q3: MFMA(mh1,nh0); issue aFx'+bF0n(T+1) reads; stage A-mh1(T+2)
    if (T + 1 < NT) {
      rd_a(rcA + ((unsigned)AOFF(b ^ 1, 0) << 1), aFx);
      rd_b(rcB + ((unsigned)BOFF(b ^ 1, 0) << 1), bF0n);
      if (T + 2 < NT) stage_A_half(A, brow, (T + 2) * BK, 1, lds + AOFF(b, 1), t);
      LGKM(12);
      MFMA16(aFy, bF0, 1, 0);
#pragma unroll
      for (int ni = 0; ni < 2; ++ni)
#pragma unroll
        for (int kk = 0; kk < 2; ++kk) bF0[ni][kk] = bF0n[ni][kk];
    } else {
      LGKM(0);
      MFMA16(aFy, bF0, 1, 0);
    }
    __builtin_amdgcn_s_barrier();
  }

  // ---- epilogue: LDS-transposed vectorized C-write ----
  // Slice = 32 rows x 256 cols f32, padded row stride 260 floats; slice s
  // owned by waves with wr == s>>2, m = {2*(s&3), 2*(s&3)+1}; then all 512
  // threads stream out dwordx4 with 256B-per-lane-group contiguity.
  {
    float* lf = (float*)&lds[0];
    float sc[4], bi[4];
#pragma unroll
    for (int n = 0; n < 4; ++n) {
      const int gc = bcol + wc * 64 + n * 16 + fr;
      sc[n] = scale[gc];
      bi[n] = bias[gc];
    }
    const int srow = t >> 4;          // 0..31
    const int scol4 = (t & 15) * 4;   // col base (floats)
#pragma unroll
    for (int s = 0; s < 8; ++s) {
      const int kmh = s & 3;
      if (wr == (s >> 3 ? 1 : (s >> 2))) {
#pragma unroll
        for (int dm = 0; dm < 2; ++dm) {
          const int m = 2 * kmh + dm;
#pragma unroll
          for (int n = 0; n < 4; ++n) {
            const int col = wc * 64 + n * 16 + fr;
#pragma unroll
            for (int j = 0; j < 4; ++j) {
              const int rin = dm * 16 + fq * 4 + j;
              lf[rin * 260 + col] = acc[m][n][j] * sc[n] + bi[n];
            }
          }
        }
      }
      __builtin_amdgcn_s_barrier();
      float* gout = C + (size_t)(brow + s * 32 + srow) * N_DIM + bcol;
#pragma unroll
      for (int k = 0; k < 4; ++k) {
        const int c0 = scol4 + k * 64;
        f32x4 v = *(const f32x4*)&lf[srow * 260 + c0];
        *(f32x4*)&gout[c0] = v;
      }
      __builtin_amdgcn_s_barrier();  // slice fully read before overwrite
    }
  }
}

// ---------------- naive fallback (only if ws too small) ----------------

__global__ void naive_kernel(const float* __restrict__ x, const int* __restrict__ w,
                             const float* __restrict__ sc, const float* __restrict__ bi,
                             float* __restrict__ out) {
  size_t idx = (size_t)blockIdx.x * blockDim.x + threadIdx.x;
  int m = (int)(idx >> 12);
  int n = (int)(idx & 4095);
  const float* xr = x + (size_t)m * K_DIM;
  const int* wr = w + (size_t)n * K_DIM;
  float acc = 0.f;
  for (int k = 0; k < K_DIM; ++k) acc = fmaf(xr[k], (float)wr[k], acc);
  out[idx] = acc * sc[n] + bi[n];
}

extern "C" void kernel_launch(void* const* d_in, const int* in_sizes, int n_in,
                              void* d_out, int out_size, void* d_ws, size_t ws_size,
                              hipStream_t stream) {
  const float* x = (const float*)d_in[0];
  const int* w = (const int*)d_in[1];
  const float* scale = (const float*)d_in[2];
  const float* bias = (const float*)d_in[3];
  float* out = (float*)d_out;

  const long nx = (long)M_DIM * K_DIM;
  const long nw = (long)N_DIM * K_DIM;
  const size_t need = (size_t)nx * 2 + (size_t)nw * 2;  // 96 MiB

  if (ws_size >= need) {
    unsigned short* xb = (unsigned short*)d_ws;
    unsigned short* wb = xb + nx;
    cvt_fused_kernel<<<2048, 256, 0, stream>>>(x, w, xb, wb, nx, nw);
    gemm_bt_kernel<<<512, 512, 0, stream>>>(xb, wb, scale, bias, out);
  } else {
    naive_kernel<<<((long)M_DIM * N_DIM) / 256, 256, 0, stream>>>(x, w, scale, bias, out);
  }
}